// Round 1
// baseline (1845.545 us; speedup 1.0000x reference)
//
#include <hip/hip_runtime.h>
#include <math.h>

typedef unsigned int u32;
typedef unsigned long long u64;

#define N_PIX 16384
#define N_ANC 147456
#define N_PRE 6000

// ws layout (bytes, 256-aligned)
#define OFF_H      0ULL            // 16384*512*4   = 33554432
#define OFF_BOXES  33554432ULL     // 147456*16     = 2359296
#define OFF_KEYS   35913728ULL     // 147456*4      = 589824
#define OFF_W54    36503552ULL     // 512*64*4      = 131072
#define OFF_B54    36634624ULL     // 64*4 -> pad 256
#define OFF_HIST1  36634880ULL     // 65536*4
#define OFF_HIST2  36897024ULL     // 65536*4
#define OFF_CTRL   37159168ULL     // 64*4 -> 256
#define OFF_CAND   37159424ULL     // 6144*8
#define OFF_TIES   37208576ULL     // 16384*4
#define OFF_SIDX   37274112ULL     // 6144*4
#define OFF_SBOX   37298688ULL     // 6144*16
#define OFF_MASK   37396992ULL     // 6016*94*8 = 4524032
#define WS_NEEDED  41921024ULL

#define KEY_NEGINF 0x007FFFFFu     // flip(bits(-inf))

struct AB { float v[36]; };

// ctrl: [0]=b1 [1]=A1 [2]=Kstar [3]=A [4]=need [5]=cntHigh [6]=cntTie [7]=L

// ---------------- init: zero hists/ctrl/roi, pack head weights ----------------
__global__ void k_init(u32* hist1, u32* hist2, u32* ctrl, float* roi,
                       float* w54, float* b54,
                       const float* __restrict__ loc_w, const float* __restrict__ loc_b,
                       const float* __restrict__ score_w, const float* __restrict__ score_b) {
  int i = blockIdx.x * blockDim.x + threadIdx.x;
  const int stride = gridDim.x * blockDim.x;
  const int TOT = 65536 * 2 + 64 + 1200 + 32768 + 64;
  for (; i < TOT; i += stride) {
    if (i < 65536) hist1[i] = 0u;
    else if (i < 131072) hist2[i - 65536] = 0u;
    else if (i < 131136) ctrl[i - 131072] = 0u;
    else if (i < 132336) roi[i - 131136] = 0.f;
    else if (i < 165104) {
      int j = i - 132336;
      int k = j >> 6, oc = j & 63;
      float v = 0.f;
      if (oc < 36) v = loc_w[k * 36 + oc];
      else if (oc < 54) v = score_w[k * 18 + oc - 36];
      // pack as float4 over k%4 for vectorized loads: w54v[(k/4)*64+oc].{k%4}
      w54[(((k >> 2) << 6) + oc) * 4 + (k & 3)] = v;
    } else {
      int oc = i - 165104;
      float v = 0.f;
      if (oc < 36) v = loc_b[oc];
      else if (oc < 54) v = score_b[oc - 36];
      b54[oc] = v;
    }
  }
}

// ---------------- 3x3 conv 512->512 + bias + relu (fp32 VALU GEMM) ----------------
// grid (128 rows, 4 n-blocks), 256 threads. BM=BN=128, BK=32, 8x8 micro-tile.
__global__ __launch_bounds__(256, 2) void k_conv(const float* __restrict__ x,
                                                 const float* __restrict__ w,
                                                 const float* __restrict__ bias,
                                                 float* __restrict__ h) {
  __shared__ float As[32][132];   // [k][m], pad 132 -> 4-way max write conflict
  __shared__ float Bs[32][128];   // [k][n]
  const int y  = blockIdx.x;
  const int nb = blockIdx.y;
  const int t  = threadIdx.x;
  const int tn = t & 15, tm = t >> 4;
  const int a_c4 = t & 7,  a_mp = t >> 3;   // A staging: channel-quad, pixel
  const int b_c  = t & 31, b_kr = t >> 5;   // B staging: col-quad, k-row

  float acc[8][8];
#pragma unroll
  for (int i = 0; i < 8; ++i)
#pragma unroll
    for (int j = 0; j < 8; ++j) acc[i][j] = 0.f;

  for (int kb = 0; kb < 144; ++kb) {
    const int tap  = kb >> 4;              // 0..8
    const int ky   = tap / 3, kx = tap - ky * 3;
    const int cin0 = (kb & 15) << 5;       // 0..480
    const int yy   = y + ky - 1;
    const bool yok = (yy >= 0) && (yy < 128);
    // stage A (transpose channels->k rows)
#pragma unroll
    for (int j = 0; j < 4; ++j) {
      const int m  = a_mp + (j << 5);
      const int xx = m + kx - 1;
      float4 v = make_float4(0.f, 0.f, 0.f, 0.f);
      if (yok && xx >= 0 && xx < 128)
        v = *(const float4*)(x + ((size_t)((yy << 7) + xx) << 9) + cin0 + (a_c4 << 2));
      As[(a_c4 << 2) + 0][m] = v.x;
      As[(a_c4 << 2) + 1][m] = v.y;
      As[(a_c4 << 2) + 2][m] = v.z;
      As[(a_c4 << 2) + 3][m] = v.w;
    }
    // stage B (already k-major x n-contiguous)
#pragma unroll
    for (int j = 0; j < 4; ++j) {
      const int kr = b_kr + (j << 3);
      float4 v = *(const float4*)(w + ((size_t)(tap * 512 + cin0 + kr) << 9) + (nb << 7) + (b_c << 2));
      *(float4*)(&Bs[kr][b_c << 2]) = v;
    }
    __syncthreads();
#pragma unroll 8
    for (int k = 0; k < 32; ++k) {
      float a0[8], b0[8];
      *(float4*)&a0[0] = *(const float4*)&As[k][tm << 2];
      *(float4*)&a0[4] = *(const float4*)&As[k][64 + (tm << 2)];
      *(float4*)&b0[0] = *(const float4*)&Bs[k][tn << 2];
      *(float4*)&b0[4] = *(const float4*)&Bs[k][64 + (tn << 2)];
#pragma unroll
      for (int i = 0; i < 8; ++i)
#pragma unroll
        for (int j = 0; j < 8; ++j) acc[i][j] += a0[i] * b0[j];
    }
    __syncthreads();
  }
  // epilogue: bias + relu -> h
#pragma unroll
  for (int i = 0; i < 8; ++i) {
    const int m = (i < 4) ? ((tm << 2) + i) : (64 + (tm << 2) + i - 4);
    float* hp = h + ((size_t)((y << 7) + m) << 9) + (nb << 7);
#pragma unroll
    for (int g = 0; g < 2; ++g) {
      const int n = (g << 6) + (tn << 2);
      float4 o;
      o.x = fmaxf(acc[i][(g << 2) + 0] + bias[(nb << 7) + n + 0], 0.f);
      o.y = fmaxf(acc[i][(g << 2) + 1] + bias[(nb << 7) + n + 1], 0.f);
      o.z = fmaxf(acc[i][(g << 2) + 2] + bias[(nb << 7) + n + 2], 0.f);
      o.w = fmaxf(acc[i][(g << 2) + 3] + bias[(nb << 7) + n + 3], 0.f);
      *(float4*)(hp + n) = o;
    }
  }
}

// ---------------- heads: 1x1 convs + outputs + softmax + loc2bbox + keys ----------------
// 256 threads = 4 waves, one pixel per wave.
__global__ __launch_bounds__(256) void k_heads(const float* __restrict__ h,
        const float4* __restrict__ w54, const float* __restrict__ b54,
        float* __restrict__ out0, float* __restrict__ out1, float* __restrict__ out3,
        float4* __restrict__ boxes, u32* __restrict__ keys,
        const int* __restrict__ p_ih, const int* __restrict__ p_iw,
        const int* __restrict__ p_sc, AB ab) {
  __shared__ float hl[4][512];
  __shared__ float vals[4][64];
  const int t = threadIdx.x;
  const int wv = t >> 6, lane = t & 63;
  const int p = (blockIdx.x << 2) + wv;

  *(float4*)&hl[wv][lane << 2]         = *(const float4*)(h + ((size_t)p << 9) + (lane << 2));
  *(float4*)&hl[wv][256 + (lane << 2)] = *(const float4*)(h + ((size_t)p << 9) + 256 + (lane << 2));
  __syncthreads();

  float acc = 0.f;
#pragma unroll 4
  for (int kq = 0; kq < 128; ++kq) {
    float4 wvv = w54[(kq << 6) + lane];
    float4 hv  = *(const float4*)&hl[wv][kq << 2];
    acc += hv.x * wvv.x + hv.y * wvv.y + hv.z * wvv.z + hv.w * wvv.w;
  }
  acc += b54[lane];
  vals[wv][lane] = acc;
  if (lane < 36) out0[p * 36 + lane] = acc;                 // rpn_loc (raw)
  else if (lane < 54) out1[p * 18 + lane - 36] = acc;       // rpn_score (raw)
  __syncthreads();

  if (lane < 9) {
    const int a = lane;
    const float l0 = vals[wv][(a << 2) + 0], l1 = vals[wv][(a << 2) + 1];
    const float l2 = vals[wv][(a << 2) + 2], l3 = vals[wv][(a << 2) + 3];
    const float s0 = vals[wv][36 + (a << 1)], s1 = vals[wv][37 + (a << 1)];
    const int yq = p >> 7, xq = p & 127;
    const float fy = (float)(yq << 4), fx = (float)(xq << 4);
    const float ay1 = ab.v[(a << 2) + 0] + fy;
    const float ax1 = ab.v[(a << 2) + 1] + fx;
    const float ay2 = ab.v[(a << 2) + 2] + fy;
    const float ax2 = ab.v[(a << 2) + 3] + fx;
    const int idx = p * 9 + a;
    *(float4*)(out3 + ((size_t)idx << 2)) = make_float4(ay1, ax1, ay2, ax2);

    const float sh = ay2 - ay1, sw = ax2 - ax1;
    const float scy = ay1 + 0.5f * sh, scx = ax1 + 0.5f * sw;
    const float cy = l0 * sh + scy, cx = l1 * sw + scx;
    const float bh = expf(l2) * sh, bw = expf(l3) * sw;
    const float IH = (float)p_ih[0], IW = (float)p_iw[0];
    float d0 = fminf(fmaxf(cy - 0.5f * bh, 0.f), IH);
    float d1 = fminf(fmaxf(cx - 0.5f * bw, 0.f), IW);
    float d2 = fminf(fmaxf(cy + 0.5f * bh, 0.f), IH);
    float d3 = fminf(fmaxf(cx + 0.5f * bw, 0.f), IW);
    boxes[idx] = make_float4(d0, d1, d2, d3);

    const float minsz = 16.f * (float)p_sc[0];
    const bool keep = (d2 - d0 >= minsz) && (d3 - d1 >= minsz);
    const float mx = fmaxf(s0, s1);
    const float e0 = expf(s0 - mx), e1 = expf(s1 - mx);
    const float fg = e1 / (e0 + e1);
    const float sc = keep ? fg : -INFINITY;
    const u32 u = __float_as_uint(sc);
    keys[idx] = (u & 0x80000000u) ? ~u : (u | 0x80000000u);  // order-preserving flip
  }
}

// ---------------- top-6000: two-level radix select ----------------
__global__ void k_hist1(const u32* __restrict__ keys, u32* __restrict__ hist1) {
  int i = blockIdx.x * blockDim.x + threadIdx.x;
  if (i < N_ANC) atomicAdd(&hist1[keys[i] >> 16], 1u);
}

__global__ void k_hist2(const u32* __restrict__ keys, const u32* __restrict__ ctrl,
                        u32* __restrict__ hist2) {
  const u32 b1 = ctrl[0];
  int i = blockIdx.x * blockDim.x + threadIdx.x;
  if (i < N_ANC) {
    const u32 k = keys[i];
    if ((k >> 16) == b1) atomicAdd(&hist2[k & 0xFFFFu], 1u);
  }
}

__global__ __launch_bounds__(1024) void k_findcut(const u32* __restrict__ hist,
                                                  u32* __restrict__ ctrl, int mode) {
  __shared__ u32 csum[1024];
  __shared__ u32 suf[1024];
  const int t = threadIdx.x;
  const u32 target = (mode == 0) ? (u32)N_PRE : ((u32)N_PRE - ctrl[1]);
  const int base = t << 6;
  u32 s = 0;
  for (int i = 0; i < 64; ++i) s += hist[base + i];
  csum[t] = s;
  suf[t] = s;
  __syncthreads();
  for (int off = 1; off < 1024; off <<= 1) {
    u32 add = (t + off < 1024) ? suf[t + off] : 0u;
    __syncthreads();
    suf[t] += add;
    __syncthreads();
  }
  const u32 excl = suf[t] - csum[t];            // count in chunks above t
  if (excl < target && target <= suf[t]) {      // exactly one thread
    u32 cum = excl;
    int bkt = base;
    for (int i = 63; i >= 0; --i) {
      const u32 hh = hist[base + i];
      if (cum < target && target <= cum + hh) { bkt = base + i; break; }
      cum += hh;
    }
    if (mode == 0) { ctrl[0] = (u32)bkt; ctrl[1] = cum; }
    else {
      const u32 Kstar = (ctrl[0] << 16) | (u32)bkt;
      const u32 A = ctrl[1] + cum;
      u32 need = (u32)N_PRE - A;
      if (Kstar == KEY_NEGINF) need = 0u;  // -inf entries never affect output
      ctrl[2] = Kstar; ctrl[3] = A; ctrl[4] = need;
    }
  }
}

__global__ void k_compact(const u32* __restrict__ keys, u32* __restrict__ ctrl,
                          u64* __restrict__ cand, u32* __restrict__ ties) {
  const u32 Kstar = ctrl[2];
  const u32 need  = ctrl[4];
  int i = blockIdx.x * blockDim.x + threadIdx.x;
  if (i >= N_ANC) return;
  const u32 k = keys[i];
  if (k > Kstar) {
    const u32 pos = atomicAdd(&ctrl[5], 1u);
    cand[pos] = ((u64)k << 32) | (u64)(u32)(~(u32)i);   // key desc, idx asc
  } else if (k == Kstar && need != 0u) {
    const u32 pos = atomicAdd(&ctrl[6], 1u);
    if (pos < 16384u) ties[pos] = (u32)i;
  }
}

__device__ inline void bitonic_desc_u64(u64* a, int n, int t) {
  for (int k = 2; k <= n; k <<= 1)
    for (int j = k >> 1; j > 0; j >>= 1) {
      __syncthreads();
      for (int i = t; i < n; i += 1024) {
        const int ixj = i ^ j;
        if (ixj > i) {
          const u64 xv = a[i], yv = a[ixj];
          if (((i & k) == 0) ? (xv < yv) : (xv > yv)) { a[i] = yv; a[ixj] = xv; }
        }
      }
    }
  __syncthreads();
}
__device__ inline void bitonic_asc_u32(u32* a, int n, int t) {
  for (int k = 2; k <= n; k <<= 1)
    for (int j = k >> 1; j > 0; j >>= 1) {
      __syncthreads();
      for (int i = t; i < n; i += 1024) {
        const int ixj = i ^ j;
        if (ixj > i) {
          const u32 xv = a[i], yv = a[ixj];
          if (((i & k) == 0) ? (xv > yv) : (xv < yv)) { a[i] = yv; a[ixj] = xv; }
        }
      }
    }
  __syncthreads();
}

__global__ __launch_bounds__(1024) void k_sort(u32* __restrict__ ctrl,
        const u64* __restrict__ cand, u32* __restrict__ ties,
        const float4* __restrict__ boxes, u32* __restrict__ sidx, float4* __restrict__ sbox) {
  __shared__ u64 arr[8192];                 // 64 KB
  u32* arr32 = (u32*)arr;
  const int t = threadIdx.x;
  const u32 A = ctrl[3];
  const u32 need = ctrl[4];
  const u32 Kstar = ctrl[2];
  const u32 tc = min(ctrl[6], 16384u);
  if (need > 0u) {                           // pick `need` smallest tie indices
    for (int i = t; i < 16384; i += 1024) arr32[i] = (i < (int)tc) ? ties[i] : 0xFFFFFFFFu;
    bitonic_asc_u32(arr32, 16384, t);
    for (int i = t; i < (int)need; i += 1024) ties[i] = arr32[i];
    __syncthreads();
  }
  for (int i = t; i < 8192; i += 1024) {
    u64 v = 0ULL;
    if (i < (int)A) v = cand[i];
    else if (i < (int)(A + need)) v = ((u64)Kstar << 32) | (u64)(u32)(~ties[i - (int)A]);
    arr[i] = v;
  }
  bitonic_desc_u64(arr, 8192, t);
  const int L = (int)(A + need);
  for (int i = t; i < L; i += 1024) {
    const u32 idx = ~((u32)(arr[i] & 0xFFFFFFFFULL));
    sidx[i] = idx;
    sbox[i] = boxes[idx];
  }
  if (t == 0) ctrl[7] = (u32)L;
}

// ---------------- NMS: suppression bitmask then single-wave greedy ----------------
__global__ __launch_bounds__(64) void k_mask(const u32* __restrict__ ctrl,
                                             const float4* __restrict__ sbox,
                                             u64* __restrict__ mask) {
  const int L = (int)ctrl[7];
  const int cw = blockIdx.x;       // col word 0..93
  const int rb = blockIdx.y;       // row block 0..93
  if (rb * 64 >= L) return;
  const int lane = threadIdx.x;
  const int j = cw * 64 + lane;
  const bool jok = (j < L);
  const float4 cb = jok ? sbox[j] : make_float4(0.f, 0.f, 0.f, 0.f);
  const float careaJ = (cb.z - cb.x) * (cb.w - cb.y);
  const int rbase = rb * 64;
  const float4 rbx = (rbase + lane < L) ? sbox[rbase + lane] : make_float4(0.f, 0.f, 0.f, 0.f);
  const int rmax = min(64, L - rbase);
  for (int r = 0; r < rmax; ++r) {
    const float ry1 = __shfl(rbx.x, r), rx1 = __shfl(rbx.y, r);
    const float ry2 = __shfl(rbx.z, r), rx2 = __shfl(rbx.w, r);
    const float ra = (ry2 - ry1) * (rx2 - rx1);
    const float iy1 = fmaxf(cb.x, ry1), ix1 = fmaxf(cb.y, rx1);
    const float iy2 = fminf(cb.z, ry2), ix2 = fminf(cb.w, rx2);
    const float inter = fmaxf(iy2 - iy1, 0.f) * fmaxf(ix2 - ix1, 0.f);
    const float iou = inter / (careaJ + ra - inter + 1e-9f);
    const bool bit = jok && (iou > 0.7f);
    const u64 bal = __ballot(bit);
    if (lane == 0) mask[(size_t)(rbase + r) * 94 + cw] = bal;
  }
}

__global__ __launch_bounds__(64) void k_greedy(const u32* __restrict__ ctrl,
                                               const float* __restrict__ sboxf,
                                               const u64* __restrict__ mask,
                                               float* __restrict__ roi) {
  const int lane = threadIdx.x;
  const int L = (int)ctrl[7];
  u64 rem0 = 0ULL, rem1 = 0ULL;    // lane w owns word w; lane w-64 owns word 64+w
  int kept = 0;
  for (int i = 0; i < L; ++i) {
    const int w = i >> 6;
    const u64 rw = (w < 64) ? __shfl(rem0, w) : __shfl(rem1, w - 64);
    if (!((rw >> (i & 63)) & 1ULL)) {
      if (lane < 4) roi[kept * 4 + lane] = sboxf[(size_t)i * 4 + lane];
      rem0 |= mask[(size_t)i * 94 + lane];
      if (lane < 30) rem1 |= mask[(size_t)i * 94 + 64 + lane];
      if (++kept == 300) break;
    }
  }
}

// ---------------- launch ----------------
extern "C" void kernel_launch(void* const* d_in, const int* in_sizes, int n_in,
                              void* d_out, int out_size, void* d_ws, size_t ws_size,
                              hipStream_t stream) {
  (void)in_sizes; (void)n_in; (void)out_size;
  if (ws_size < WS_NEEDED) return;

  const float* x       = (const float*)d_in[0];
  const float* conv_w  = (const float*)d_in[1];
  const float* conv_b  = (const float*)d_in[2];
  const float* loc_w   = (const float*)d_in[3];
  const float* loc_b   = (const float*)d_in[4];
  const float* score_w = (const float*)d_in[5];
  const float* score_b = (const float*)d_in[6];
  const int* p_ih = (const int*)d_in[7];
  const int* p_iw = (const int*)d_in[8];
  const int* p_sc = (const int*)d_in[9];

  float* out0 = (float*)d_out;         // rpn_loc   589824
  float* out1 = out0 + 589824;         // rpn_score 294912
  float* roi  = out1 + 294912;         // roi       1200
  float* out3 = roi + 1200;            // anchor    589824

  char* ws = (char*)d_ws;
  float*  h     = (float*)(ws + OFF_H);
  float4* boxes = (float4*)(ws + OFF_BOXES);
  u32*    keys  = (u32*)(ws + OFF_KEYS);
  float*  w54   = (float*)(ws + OFF_W54);
  float*  b54   = (float*)(ws + OFF_B54);
  u32*    hist1 = (u32*)(ws + OFF_HIST1);
  u32*    hist2 = (u32*)(ws + OFF_HIST2);
  u32*    ctrl  = (u32*)(ws + OFF_CTRL);
  u64*    cand  = (u64*)(ws + OFF_CAND);
  u32*    ties  = (u32*)(ws + OFF_TIES);
  u32*    sidx  = (u32*)(ws + OFF_SIDX);
  float4* sbox  = (float4*)(ws + OFF_SBOX);
  u64*    mask  = (u64*)(ws + OFF_MASK);

  AB ab;
  {
    const double ratios[3] = {0.5, 1.0, 2.0};
    const double scales[3] = {8.0, 16.0, 32.0};
    for (int i = 0; i < 3; ++i)
      for (int j = 0; j < 3; ++j) {
        const double hh = 16.0 * scales[j] * sqrt(ratios[i]);
        const double wwv = 16.0 * scales[j] * sqrt(1.0 / ratios[i]);
        const int a = i * 3 + j;
        ab.v[a * 4 + 0] = (float)(8.0 - hh / 2.0);
        ab.v[a * 4 + 1] = (float)(8.0 - wwv / 2.0);
        ab.v[a * 4 + 2] = (float)(8.0 + hh / 2.0);
        ab.v[a * 4 + 3] = (float)(8.0 + wwv / 2.0);
      }
  }

  hipLaunchKernelGGL(k_init, dim3(256), dim3(256), 0, stream,
                     hist1, hist2, ctrl, roi, w54, b54, loc_w, loc_b, score_w, score_b);
  hipLaunchKernelGGL(k_conv, dim3(128, 4), dim3(256), 0, stream, x, conv_w, conv_b, h);
  hipLaunchKernelGGL(k_heads, dim3(4096), dim3(256), 0, stream,
                     h, (const float4*)w54, b54, out0, out1, out3, boxes, keys,
                     p_ih, p_iw, p_sc, ab);
  hipLaunchKernelGGL(k_hist1, dim3(576), dim3(256), 0, stream, keys, hist1);
  hipLaunchKernelGGL(k_findcut, dim3(1), dim3(1024), 0, stream, hist1, ctrl, 0);
  hipLaunchKernelGGL(k_hist2, dim3(576), dim3(256), 0, stream, keys, ctrl, hist2);
  hipLaunchKernelGGL(k_findcut, dim3(1), dim3(1024), 0, stream, hist2, ctrl, 1);
  hipLaunchKernelGGL(k_compact, dim3(576), dim3(256), 0, stream, keys, ctrl, cand, ties);
  hipLaunchKernelGGL(k_sort, dim3(1), dim3(1024), 0, stream, ctrl, cand, ties, boxes, sidx, sbox);
  hipLaunchKernelGGL(k_mask, dim3(94, 94), dim3(64), 0, stream, ctrl, sbox, mask);
  hipLaunchKernelGGL(k_greedy, dim3(1), dim3(64), 0, stream, ctrl, (const float*)sbox, mask, roi);
}

// Round 2
// 893.398 us; speedup vs baseline: 2.0658x; 2.0658x over previous
//
#include <hip/hip_runtime.h>
#include <math.h>

typedef unsigned int u32;
typedef unsigned long long u64;
typedef _Float16 half8 __attribute__((ext_vector_type(8)));
typedef float f32x4 __attribute__((ext_vector_type(4)));

#define N_PIX 16384
#define N_ANC 147456
#define N_PRE 6000

// ws layout (bytes, 256-aligned)
#define OFF_H      0ULL            // 16384*512*4   = 33554432
#define OFF_BOXES  33554432ULL     // 147456*16     = 2359296
#define OFF_KEYS   35913728ULL     // 147456*4      = 589824
#define OFF_W54    36503552ULL     // 512*64*4      = 131072
#define OFF_B54    36634624ULL     // 64*4 -> pad 256
#define OFF_HIST1  36634880ULL     // 65536*4
#define OFF_HIST2  36897024ULL     // 65536*4
#define OFF_CTRL   37159168ULL     // 64*4 -> 256
#define OFF_CAND   37159424ULL     // 6144*8
#define OFF_TIES   37208576ULL     // 16384*4
#define OFF_SIDX   37274112ULL     // 6144*4 (unused, kept for layout)
#define OFF_SBOX   37298688ULL     // 6144*16
#define OFF_MASK   37396992ULL     // 6016*94*8 = 4524032
#define WS_NEEDED  41921024ULL

#define KEY_NEGINF 0x007FFFFFu     // flip(bits(-inf))

struct AB { float v[36]; };

// ctrl: [0]=b1 [1]=A1 [2]=Kstar [3]=A [4]=need [5]=cntHigh [6]=cntTie [7]=L

// ---------------- init: zero hists/ctrl/roi, pack head weights ----------------
__global__ void k_init(u32* hist1, u32* hist2, u32* ctrl, float* roi,
                       float* w54, float* b54,
                       const float* __restrict__ loc_w, const float* __restrict__ loc_b,
                       const float* __restrict__ score_w, const float* __restrict__ score_b) {
  int i = blockIdx.x * blockDim.x + threadIdx.x;
  const int stride = gridDim.x * blockDim.x;
  const int TOT = 65536 * 2 + 64 + 1200 + 32768 + 64;
  for (; i < TOT; i += stride) {
    if (i < 65536) hist1[i] = 0u;
    else if (i < 131072) hist2[i - 65536] = 0u;
    else if (i < 131136) ctrl[i - 131072] = 0u;
    else if (i < 132336) roi[i - 131136] = 0.f;
    else if (i < 165104) {
      int j = i - 132336;
      int k = j >> 6, oc = j & 63;
      float v = 0.f;
      if (oc < 36) v = loc_w[k * 36 + oc];
      else if (oc < 54) v = score_w[k * 18 + oc - 36];
      w54[(((k >> 2) << 6) + oc) * 4 + (k & 3)] = v;
    } else {
      int oc = i - 165104;
      float v = 0.f;
      if (oc < 36) v = loc_b[oc];
      else if (oc < 54) v = score_b[oc - 36];
      b54[oc] = v;
    }
  }
}

// ---------------- 3x3 conv 512->512 + bias + relu via fp16-split MFMA ----------------
// x = xh + xl*2^-11 (fp16 each, xl prescaled by 2^11), same for w.
// h = sum xh*wh  +  2^-11 * sum (xh*wl + xl*wh).   (lo*lo dropped: ~2^-22 rel)
// grid (128 rows, 4 n-blocks), 256 threads = 4 waves (2x2), wave tile 64x64,
// 4x4 grid of mfma_f32_16x16x32_f16, BK=32.
#define APAD 40   // row stride in halfs: 80 B, 16B-aligned fragments
__global__ __launch_bounds__(256, 2) void k_conv(const float* __restrict__ x,
                                                 const float* __restrict__ w,
                                                 const float* __restrict__ bias,
                                                 float* __restrict__ h) {
  __shared__ _Float16 Ah[128][APAD];
  __shared__ _Float16 Al[128][APAD];
  __shared__ _Float16 Bh[128][APAD];
  __shared__ _Float16 Bl[128][APAD];

  const int y  = blockIdx.x;
  const int nb = blockIdx.y;
  const int t  = threadIdx.x;
  const int wv = t >> 6, lane = t & 63;
  const int m0 = (wv >> 1) << 6;           // wave m origin (0/64)
  const int n0 = (wv & 1) << 6;            // wave n origin (0/64)
  const int fm = lane & 15;                // fragment row/col within 16
  const int fq = lane >> 4;                // k-quad (0..3) -> k offset 8*fq

  // staging assignments
  const int sa_m = t >> 1;                 // A: pixel 0..127
  const int sa_h = (t & 1) << 4;           // A: 16-channel half (0/16)
  const int sb_n = t & 127;                // B: col 0..127
  const int sb_kg = (t >> 7) << 4;         // B: k offset (0/16)

  f32x4 acc_hh[4][4];
  f32x4 acc_x[4][4];
#pragma unroll
  for (int i = 0; i < 4; ++i)
#pragma unroll
    for (int j = 0; j < 4; ++j) { acc_hh[i][j] = (f32x4)0.f; acc_x[i][j] = (f32x4)0.f; }

#pragma unroll 1
  for (int kb = 0; kb < 144; ++kb) {
    const int tap  = kb >> 4;
    const int ky   = tap / 3, kx = tap - ky * 3;
    const int cin0 = (kb & 15) << 5;

    // ---- stage A: 128 pixels x 32 channels fp32 -> hi/lo fp16 ----
    {
      const int yy = y + ky - 1;
      const int xx = sa_m + kx - 1;
      float av[16];
      if (yy >= 0 && yy < 128 && xx >= 0 && xx < 128) {
        const float* ap = x + (((size_t)((yy << 7) + xx)) << 9) + cin0 + sa_h;
#pragma unroll
        for (int j = 0; j < 4; ++j) *(float4*)&av[j << 2] = *(const float4*)(ap + (j << 2));
      } else {
#pragma unroll
        for (int j = 0; j < 16; ++j) av[j] = 0.f;
      }
      half8 h0, h1, l0, l1;
#pragma unroll
      for (int j = 0; j < 8; ++j) {
        _Float16 hi = (_Float16)av[j];
        h0[j] = hi;
        l0[j] = (_Float16)((av[j] - (float)hi) * 2048.0f);
      }
#pragma unroll
      for (int j = 0; j < 8; ++j) {
        _Float16 hi = (_Float16)av[8 + j];
        h1[j] = hi;
        l1[j] = (_Float16)((av[8 + j] - (float)hi) * 2048.0f);
      }
      *(half8*)&Ah[sa_m][sa_h]     = h0;
      *(half8*)&Ah[sa_m][sa_h + 8] = h1;
      *(half8*)&Al[sa_m][sa_h]     = l0;
      *(half8*)&Al[sa_m][sa_h + 8] = l1;
    }
    // ---- stage B: 32 k x 128 n fp32 -> hi/lo fp16 (transposed to [n][k]) ----
    {
      const float* bp = w + ((size_t)(tap * 512 + cin0 + sb_kg) << 9) + (nb << 7) + sb_n;
      float bv[16];
#pragma unroll
      for (int j = 0; j < 16; ++j) bv[j] = bp[(size_t)j << 9];
      half8 h0, h1, l0, l1;
#pragma unroll
      for (int j = 0; j < 8; ++j) {
        _Float16 hi = (_Float16)bv[j];
        h0[j] = hi;
        l0[j] = (_Float16)((bv[j] - (float)hi) * 2048.0f);
      }
#pragma unroll
      for (int j = 0; j < 8; ++j) {
        _Float16 hi = (_Float16)bv[8 + j];
        h1[j] = hi;
        l1[j] = (_Float16)((bv[8 + j] - (float)hi) * 2048.0f);
      }
      *(half8*)&Bh[sb_n][sb_kg]     = h0;
      *(half8*)&Bh[sb_n][sb_kg + 8] = h1;
      *(half8*)&Bl[sb_n][sb_kg]     = l0;
      *(half8*)&Bl[sb_n][sb_kg + 8] = l1;
    }
    __syncthreads();

    // ---- fragments + MFMA ----
    half8 ah[4], al[4], bh[4], bl[4];
#pragma unroll
    for (int i = 0; i < 4; ++i) {
      ah[i] = *(const half8*)&Ah[m0 + (i << 4) + fm][fq << 3];
      al[i] = *(const half8*)&Al[m0 + (i << 4) + fm][fq << 3];
      bh[i] = *(const half8*)&Bh[n0 + (i << 4) + fm][fq << 3];
      bl[i] = *(const half8*)&Bl[n0 + (i << 4) + fm][fq << 3];
    }
#pragma unroll
    for (int mi = 0; mi < 4; ++mi)
#pragma unroll
      for (int ni = 0; ni < 4; ++ni) {
        acc_hh[mi][ni] = __builtin_amdgcn_mfma_f32_16x16x32_f16(ah[mi], bh[ni], acc_hh[mi][ni], 0, 0, 0);
        acc_x[mi][ni]  = __builtin_amdgcn_mfma_f32_16x16x32_f16(ah[mi], bl[ni], acc_x[mi][ni], 0, 0, 0);
        acc_x[mi][ni]  = __builtin_amdgcn_mfma_f32_16x16x32_f16(al[mi], bh[ni], acc_x[mi][ni], 0, 0, 0);
      }
    __syncthreads();
  }

  // ---- epilogue: combine, bias, relu, store ----
  const float inv2048 = 1.0f / 2048.0f;
#pragma unroll
  for (int mi = 0; mi < 4; ++mi)
#pragma unroll
    for (int ni = 0; ni < 4; ++ni) {
      const int col = n0 + (ni << 4) + fm;
      const float bb = bias[(nb << 7) + col];
#pragma unroll
      for (int r = 0; r < 4; ++r) {
        const int row = m0 + (mi << 4) + (fq << 2) + r;
        float v = acc_hh[mi][ni][r] + acc_x[mi][ni][r] * inv2048 + bb;
        h[(((size_t)((y << 7) + row)) << 9) + (nb << 7) + col] = fmaxf(v, 0.f);
      }
    }
}

// ---------------- heads: 1x1 convs + softmax + loc2bbox + keys ----------------
// 256 threads = 4 waves; each wave does 4 pixels (w54 float4 reused 16x).
__global__ __launch_bounds__(256) void k_heads(const float* __restrict__ h,
        const float4* __restrict__ w54, const float* __restrict__ b54,
        float* __restrict__ out0, float* __restrict__ out1, float* __restrict__ out3,
        float4* __restrict__ boxes, u32* __restrict__ keys,
        const int* __restrict__ p_ih, const int* __restrict__ p_iw,
        const int* __restrict__ p_sc, AB ab) {
  __shared__ float hl[16 * 512];
  __shared__ float vals[16][64];
  const int t = threadIdx.x;
  const int wv = t >> 6, lane = t & 63;
  const int pbase = blockIdx.x << 4;

#pragma unroll
  for (int j = 0; j < 8; ++j) {
    const int f = (j << 8) + t;
    ((float4*)hl)[f] = ((const float4*)(h + ((size_t)pbase << 9)))[f];
  }
  __syncthreads();

  const float* hp = hl + ((wv << 2) << 9);
  float a0 = 0.f, a1 = 0.f, a2 = 0.f, a3 = 0.f;
#pragma unroll 4
  for (int kq = 0; kq < 128; ++kq) {
    const float4 wvv = w54[(kq << 6) + lane];
    const float4 h0 = *(const float4*)(hp + (kq << 2));
    const float4 h1 = *(const float4*)(hp + 512 + (kq << 2));
    const float4 h2 = *(const float4*)(hp + 1024 + (kq << 2));
    const float4 h3 = *(const float4*)(hp + 1536 + (kq << 2));
    a0 += h0.x * wvv.x + h0.y * wvv.y + h0.z * wvv.z + h0.w * wvv.w;
    a1 += h1.x * wvv.x + h1.y * wvv.y + h1.z * wvv.z + h1.w * wvv.w;
    a2 += h2.x * wvv.x + h2.y * wvv.y + h2.z * wvv.z + h2.w * wvv.w;
    a3 += h3.x * wvv.x + h3.y * wvv.y + h3.z * wvv.z + h3.w * wvv.w;
  }
  const float bb = b54[lane];
  float av[4] = {a0 + bb, a1 + bb, a2 + bb, a3 + bb};
#pragma unroll
  for (int px = 0; px < 4; ++px) {
    const int p = pbase + (wv << 2) + px;
    vals[(wv << 2) + px][lane] = av[px];
    if (lane < 36) out0[p * 36 + lane] = av[px];
    else if (lane < 54) out1[p * 18 + lane - 36] = av[px];
  }
  __syncthreads();

  if (lane < 36) {
    const int px = lane / 9, a = lane - px * 9;
    const int p = pbase + (wv << 2) + px;
    const float* vv = vals[(wv << 2) + px];
    const float l0 = vv[(a << 2) + 0], l1 = vv[(a << 2) + 1];
    const float l2 = vv[(a << 2) + 2], l3 = vv[(a << 2) + 3];
    const float s0 = vv[36 + (a << 1)], s1 = vv[37 + (a << 1)];
    const int yq = p >> 7, xq = p & 127;
    const float fy = (float)(yq << 4), fx = (float)(xq << 4);
    const float ay1 = ab.v[(a << 2) + 0] + fy;
    const float ax1 = ab.v[(a << 2) + 1] + fx;
    const float ay2 = ab.v[(a << 2) + 2] + fy;
    const float ax2 = ab.v[(a << 2) + 3] + fx;
    const int idx = p * 9 + a;
    *(float4*)(out3 + ((size_t)idx << 2)) = make_float4(ay1, ax1, ay2, ax2);

    const float sh = ay2 - ay1, sw = ax2 - ax1;
    const float scy = ay1 + 0.5f * sh, scx = ax1 + 0.5f * sw;
    const float cy = l0 * sh + scy, cx = l1 * sw + scx;
    const float bh = expf(l2) * sh, bw = expf(l3) * sw;
    const float IH = (float)p_ih[0], IW = (float)p_iw[0];
    float d0 = fminf(fmaxf(cy - 0.5f * bh, 0.f), IH);
    float d1 = fminf(fmaxf(cx - 0.5f * bw, 0.f), IW);
    float d2 = fminf(fmaxf(cy + 0.5f * bh, 0.f), IH);
    float d3 = fminf(fmaxf(cx + 0.5f * bw, 0.f), IW);
    boxes[idx] = make_float4(d0, d1, d2, d3);

    const float minsz = 16.f * (float)p_sc[0];
    const bool keep = (d2 - d0 >= minsz) && (d3 - d1 >= minsz);
    const float mx = fmaxf(s0, s1);
    const float e0 = expf(s0 - mx), e1 = expf(s1 - mx);
    const float fg = e1 / (e0 + e1);
    const float sc = keep ? fg : -INFINITY;
    const u32 u = __float_as_uint(sc);
    keys[idx] = (u & 0x80000000u) ? ~u : (u | 0x80000000u);
  }
}

// ---------------- top-6000: two-level radix select ----------------
__global__ void k_hist1(const u32* __restrict__ keys, u32* __restrict__ hist1) {
  int i = blockIdx.x * blockDim.x + threadIdx.x;
  if (i < N_ANC) atomicAdd(&hist1[keys[i] >> 16], 1u);
}

__global__ void k_hist2(const u32* __restrict__ keys, const u32* __restrict__ ctrl,
                        u32* __restrict__ hist2) {
  const u32 b1 = ctrl[0];
  int i = blockIdx.x * blockDim.x + threadIdx.x;
  if (i < N_ANC) {
    const u32 k = keys[i];
    if ((k >> 16) == b1) atomicAdd(&hist2[k & 0xFFFFu], 1u);
  }
}

__global__ __launch_bounds__(1024) void k_findcut(const u32* __restrict__ hist,
                                                  u32* __restrict__ ctrl, int mode) {
  __shared__ u32 csum[1024];
  __shared__ u32 suf[1024];
  const int t = threadIdx.x;
  const u32 target = (mode == 0) ? (u32)N_PRE : ((u32)N_PRE - ctrl[1]);
  const int base = t << 6;
  u32 s = 0;
  for (int i = 0; i < 64; ++i) s += hist[base + i];
  csum[t] = s;
  suf[t] = s;
  __syncthreads();
  for (int off = 1; off < 1024; off <<= 1) {
    u32 add = (t + off < 1024) ? suf[t + off] : 0u;
    __syncthreads();
    suf[t] += add;
    __syncthreads();
  }
  const u32 excl = suf[t] - csum[t];
  if (excl < target && target <= suf[t]) {
    u32 cum = excl;
    int bkt = base;
    for (int i = 63; i >= 0; --i) {
      const u32 hh = hist[base + i];
      if (cum < target && target <= cum + hh) { bkt = base + i; break; }
      cum += hh;
    }
    if (mode == 0) { ctrl[0] = (u32)bkt; ctrl[1] = cum; }
    else {
      const u32 Kstar = (ctrl[0] << 16) | (u32)bkt;
      const u32 A = ctrl[1] + cum;
      u32 need = (u32)N_PRE - A;
      if (Kstar == KEY_NEGINF) need = 0u;
      ctrl[2] = Kstar; ctrl[3] = A; ctrl[4] = need;
    }
  }
}

__global__ void k_compact(const u32* __restrict__ keys, u32* __restrict__ ctrl,
                          u64* __restrict__ cand, u32* __restrict__ ties) {
  const u32 Kstar = ctrl[2];
  const u32 need  = ctrl[4];
  int i = blockIdx.x * blockDim.x + threadIdx.x;
  if (i >= N_ANC) return;
  const u32 k = keys[i];
  if (k > Kstar) {
    const u32 pos = atomicAdd(&ctrl[5], 1u);
    cand[pos] = ((u64)k << 32) | (u64)(u32)(~(u32)i);
  } else if (k == Kstar && need != 0u) {
    const u32 pos = atomicAdd(&ctrl[6], 1u);
    if (pos < 16384u) ties[pos] = (u32)i;
  }
}

__device__ inline void bitonic_desc_u64(u64* a, int n, int t) {
  for (int k = 2; k <= n; k <<= 1)
    for (int j = k >> 1; j > 0; j >>= 1) {
      __syncthreads();
      for (int i = t; i < n; i += 1024) {
        const int ixj = i ^ j;
        if (ixj > i) {
          const u64 xv = a[i], yv = a[ixj];
          if (((i & k) == 0) ? (xv < yv) : (xv > yv)) { a[i] = yv; a[ixj] = xv; }
        }
      }
    }
  __syncthreads();
}

__global__ __launch_bounds__(1024) void k_sort(u32* __restrict__ ctrl,
        const u64* __restrict__ cand, u32* __restrict__ ties,
        const float4* __restrict__ boxes, float4* __restrict__ sbox) {
  __shared__ u64 arr[8192];                 // 64 KB
  __shared__ u64 red[1024];
  u32* arr32 = (u32*)arr;
  const int t = threadIdx.x;
  const u32 A = ctrl[3];
  const u32 need = ctrl[4];
  const u32 Kstar = ctrl[2];
  const int tc = (int)min(ctrl[6], 16384u);

  if (need > 0u) {                          // select `need` smallest tie indices
    for (int i = t; i < tc; i += 1024) arr32[i] = ties[i];
    __syncthreads();
    for (u32 r = 0; r < need; ++r) {
      u64 best = ~0ULL;
      for (int i = t; i < tc; i += 1024) {
        const u64 v = ((u64)arr32[i] << 32) | (u32)i;
        if (v < best) best = v;
      }
      red[t] = best;
      __syncthreads();
      for (int off = 512; off > 0; off >>= 1) {
        if (t < off && red[t + off] < red[t]) red[t] = red[t + off];
        __syncthreads();
      }
      if (t == 0) {
        const u32 slot = (u32)(red[0] & 0xFFFFFFFFu);
        ties[r] = (u32)(red[0] >> 32);
        arr32[slot] = 0xFFFFFFFFu;
      }
      __syncthreads();
    }
  }
  for (int i = t; i < 8192; i += 1024) {
    u64 v = 0ULL;
    if (i < (int)A) v = cand[i];
    else if (i < (int)(A + need)) v = ((u64)Kstar << 32) | (u64)(u32)(~ties[i - (int)A]);
    arr[i] = v;
  }
  bitonic_desc_u64(arr, 8192, t);
  const int L = (int)(A + need);
  for (int i = t; i < L; i += 1024) {
    const u32 idx = ~((u32)(arr[i] & 0xFFFFFFFFULL));
    sbox[i] = boxes[idx];
  }
  if (t == 0) ctrl[7] = (u32)L;
}

// ---------------- NMS: suppression bitmask then single-wave greedy skip-scan ----------------
__global__ __launch_bounds__(64) void k_mask(const u32* __restrict__ ctrl,
                                             const float4* __restrict__ sbox,
                                             u64* __restrict__ mask) {
  const int L = (int)ctrl[7];
  const int cw = blockIdx.x;       // col word 0..93
  const int rb = blockIdx.y;       // row block 0..93
  if (rb * 64 >= L) return;
  const int lane = threadIdx.x;
  const int j = cw * 64 + lane;
  const bool jok = (j < L);
  const float4 cb = jok ? sbox[j] : make_float4(0.f, 0.f, 0.f, 0.f);
  const float careaJ = (cb.z - cb.x) * (cb.w - cb.y);
  const int rbase = rb * 64;
  const float4 rbx = (rbase + lane < L) ? sbox[rbase + lane] : make_float4(0.f, 0.f, 0.f, 0.f);
  const int rmax = min(64, L - rbase);
  for (int r = 0; r < rmax; ++r) {
    const float ry1 = __shfl(rbx.x, r), rx1 = __shfl(rbx.y, r);
    const float ry2 = __shfl(rbx.z, r), rx2 = __shfl(rbx.w, r);
    const float ra = (ry2 - ry1) * (rx2 - rx1);
    const float iy1 = fmaxf(cb.x, ry1), ix1 = fmaxf(cb.y, rx1);
    const float iy2 = fminf(cb.z, ry2), ix2 = fminf(cb.w, rx2);
    const float inter = fmaxf(iy2 - iy1, 0.f) * fmaxf(ix2 - ix1, 0.f);
    const float iou = inter / (careaJ + ra - inter + 1e-9f);
    const bool bit = jok && (iou > 0.7f);
    const u64 bal = __ballot(bit);
    if (lane == 0) mask[(size_t)(rbase + r) * 94 + cw] = bal;
  }
}

__device__ inline u64 valid_mask_fn(int base, int L) {
  const int r = L - base;
  if (r <= 0) return 0ULL;
  if (r >= 64) return ~0ULL;
  return (1ULL << r) - 1ULL;
}
__device__ inline u64 above_mask_fn(int base, int i) {
  if (i < base) return ~0ULL;
  const int s = i - base + 1;
  if (s >= 64) return 0ULL;
  return (~0ULL) << s;
}

__global__ __launch_bounds__(64) void k_greedy(const u32* __restrict__ ctrl,
                                               const float* __restrict__ sboxf,
                                               const u64* __restrict__ mask,
                                               float* __restrict__ roi) {
  const int lane = threadIdx.x;
  const int L = (int)ctrl[7];
  const int base0 = lane << 6;
  const int base1 = (64 + lane) << 6;
  const u64 v0 = valid_mask_fn(base0, L);
  const u64 v1 = (lane < 30) ? valid_mask_fn(base1, L) : 0ULL;
  u64 rem0 = 0ULL, rem1 = 0ULL;
  int i = (L > 0) ? 0 : -1;
  int kept = 0;
  while (i >= 0 && kept < 300) {
    if (lane < 4) roi[kept * 4 + lane] = sboxf[(size_t)i * 4 + lane];
    ++kept;
    rem0 |= mask[(size_t)i * 94 + lane];
    if (lane < 30) rem1 |= mask[(size_t)i * 94 + 64 + lane];
    const u64 f0 = ~rem0 & v0 & above_mask_fn(base0, i);
    const u64 f1 = ~rem1 & v1 & above_mask_fn(base1, i);
    int c0 = f0 ? (base0 + (int)__builtin_ctzll(f0)) : 0x7FFFFFFF;
    int c1 = f1 ? (base1 + (int)__builtin_ctzll(f1)) : 0x7FFFFFFF;
    int c = min(c0, c1);
#pragma unroll
    for (int off = 1; off < 64; off <<= 1) c = min(c, __shfl_xor(c, off));
    i = (c == 0x7FFFFFFF) ? -1 : c;
  }
}

// ---------------- launch ----------------
extern "C" void kernel_launch(void* const* d_in, const int* in_sizes, int n_in,
                              void* d_out, int out_size, void* d_ws, size_t ws_size,
                              hipStream_t stream) {
  (void)in_sizes; (void)n_in; (void)out_size;
  if (ws_size < WS_NEEDED) return;

  const float* x       = (const float*)d_in[0];
  const float* conv_w  = (const float*)d_in[1];
  const float* conv_b  = (const float*)d_in[2];
  const float* loc_w   = (const float*)d_in[3];
  const float* loc_b   = (const float*)d_in[4];
  const float* score_w = (const float*)d_in[5];
  const float* score_b = (const float*)d_in[6];
  const int* p_ih = (const int*)d_in[7];
  const int* p_iw = (const int*)d_in[8];
  const int* p_sc = (const int*)d_in[9];

  float* out0 = (float*)d_out;         // rpn_loc   589824
  float* out1 = out0 + 589824;         // rpn_score 294912
  float* roi  = out1 + 294912;         // roi       1200
  float* out3 = roi + 1200;            // anchor    589824

  char* ws = (char*)d_ws;
  float*  h     = (float*)(ws + OFF_H);
  float4* boxes = (float4*)(ws + OFF_BOXES);
  u32*    keys  = (u32*)(ws + OFF_KEYS);
  float*  w54   = (float*)(ws + OFF_W54);
  float*  b54   = (float*)(ws + OFF_B54);
  u32*    hist1 = (u32*)(ws + OFF_HIST1);
  u32*    hist2 = (u32*)(ws + OFF_HIST2);
  u32*    ctrl  = (u32*)(ws + OFF_CTRL);
  u64*    cand  = (u64*)(ws + OFF_CAND);
  u32*    ties  = (u32*)(ws + OFF_TIES);
  float4* sbox  = (float4*)(ws + OFF_SBOX);
  u64*    mask  = (u64*)(ws + OFF_MASK);

  AB ab;
  {
    const double ratios[3] = {0.5, 1.0, 2.0};
    const double scales[3] = {8.0, 16.0, 32.0};
    for (int i = 0; i < 3; ++i)
      for (int j = 0; j < 3; ++j) {
        const double hh = 16.0 * scales[j] * sqrt(ratios[i]);
        const double wwv = 16.0 * scales[j] * sqrt(1.0 / ratios[i]);
        const int a = i * 3 + j;
        ab.v[a * 4 + 0] = (float)(8.0 - hh / 2.0);
        ab.v[a * 4 + 1] = (float)(8.0 - wwv / 2.0);
        ab.v[a * 4 + 2] = (float)(8.0 + hh / 2.0);
        ab.v[a * 4 + 3] = (float)(8.0 + wwv / 2.0);
      }
  }

  hipLaunchKernelGGL(k_init, dim3(256), dim3(256), 0, stream,
                     hist1, hist2, ctrl, roi, w54, b54, loc_w, loc_b, score_w, score_b);
  hipLaunchKernelGGL(k_conv, dim3(128, 4), dim3(256), 0, stream, x, conv_w, conv_b, h);
  hipLaunchKernelGGL(k_heads, dim3(1024), dim3(256), 0, stream,
                     h, (const float4*)w54, b54, out0, out1, out3, boxes, keys,
                     p_ih, p_iw, p_sc, ab);
  hipLaunchKernelGGL(k_hist1, dim3(576), dim3(256), 0, stream, keys, hist1);
  hipLaunchKernelGGL(k_findcut, dim3(1), dim3(1024), 0, stream, hist1, ctrl, 0);
  hipLaunchKernelGGL(k_hist2, dim3(576), dim3(256), 0, stream, keys, ctrl, hist2);
  hipLaunchKernelGGL(k_findcut, dim3(1), dim3(1024), 0, stream, hist2, ctrl, 1);
  hipLaunchKernelGGL(k_compact, dim3(576), dim3(256), 0, stream, keys, ctrl, cand, ties);
  hipLaunchKernelGGL(k_sort, dim3(1), dim3(1024), 0, stream, ctrl, cand, ties, boxes, sbox);
  hipLaunchKernelGGL(k_mask, dim3(94, 94), dim3(64), 0, stream, ctrl, sbox, mask);
  hipLaunchKernelGGL(k_greedy, dim3(1), dim3(64), 0, stream, ctrl, (const float*)sbox, mask, roi);
}

// Round 3
// 772.640 us; speedup vs baseline: 2.3886x; 1.1563x over previous
//
#include <hip/hip_runtime.h>
#include <math.h>

typedef unsigned int u32;
typedef unsigned long long u64;
typedef _Float16 half8 __attribute__((ext_vector_type(8)));
typedef float f32x4 __attribute__((ext_vector_type(4)));

#define N_PIX 16384
#define N_ANC 147456
#define N_PRE 6000
#define TIE_BASE 6144
#define TIE_CAP  16384

// ws layout (bytes)
#define OFF_H      0ULL            // 16384*512*4 = 33554432
#define OFF_BOXES  33554432ULL     // 147456*16   = 2359296
#define OFF_KEYS   35913728ULL     // 147456*4    = 589824
#define OFF_W54    36503552ULL     // 131072
#define OFF_B54    36634624ULL     // 256
#define OFF_HIST1  36634880ULL     // 262144
#define OFF_HIST2  36897024ULL     // 262144
#define OFF_CTRL   37159168ULL     // 256
#define OFF_CAND   37159424ULL     // (6144+16384)*8 = 180224
#define OFF_SBOX   37339648ULL     // 6144*16 = 98304
#define OFF_MASK   37437952ULL     // 6016*94*8 = 4524032
#define BASE_NEEDED 41961984ULL
#define OFF_XH     41961984ULL     // 16777216 (fp16)
#define OFF_XL     58739200ULL     // 16777216
#define OFF_WHT    75516416ULL     // 4718592  (fp16, [n 512][k 4608])
#define OFF_WLT    80235008ULL     // 4718592
#define FULL_NEEDED 84953600ULL

#define KEY_NEGINF 0x007FFFFFu     // flip(bits(-inf))

struct AB { float v[36]; };

// ctrl: [0]=b1 [1]=A1 [2]=Kstar [3]=A [4]=need [5]=cntHigh [6]=cntTie [7]=L

// ---------------- init ----------------
__global__ void k_init(u32* hist1, u32* hist2, u32* ctrl, float* roi,
                       float* w54, float* b54,
                       const float* __restrict__ loc_w, const float* __restrict__ loc_b,
                       const float* __restrict__ score_w, const float* __restrict__ score_b) {
  int i = blockIdx.x * blockDim.x + threadIdx.x;
  const int stride = gridDim.x * blockDim.x;
  const int TOT = 65536 * 2 + 64 + 1200 + 32768 + 64;
  for (; i < TOT; i += stride) {
    if (i < 65536) hist1[i] = 0u;
    else if (i < 131072) hist2[i - 65536] = 0u;
    else if (i < 131136) ctrl[i - 131072] = 0u;
    else if (i < 132336) roi[i - 131136] = 0.f;
    else if (i < 165104) {
      int j = i - 132336;
      int k = j >> 6, oc = j & 63;
      float v = 0.f;
      if (oc < 36) v = loc_w[k * 36 + oc];
      else if (oc < 54) v = score_w[k * 18 + oc - 36];
      w54[(((k >> 2) << 6) + oc) * 4 + (k & 3)] = v;
    } else {
      int oc = i - 165104;
      float v = 0.f;
      if (oc < 36) v = loc_b[oc];
      else if (oc < 54) v = score_b[oc - 36];
      b54[oc] = v;
    }
  }
}

// ---------------- pre-split x into fp16 hi/lo ----------------
__global__ __launch_bounds__(256) void k_split_x(const float* __restrict__ x,
                                                 _Float16* __restrict__ xh,
                                                 _Float16* __restrict__ xl) {
  const int gid = blockIdx.x * blockDim.x + threadIdx.x;   // 4096*256 threads
  const int base = gid << 3;
  float a[8];
  *(float4*)&a[0] = *(const float4*)(x + base);
  *(float4*)&a[4] = *(const float4*)(x + base + 4);
  half8 hh, ll;
#pragma unroll
  for (int j = 0; j < 8; ++j) {
    _Float16 hi = (_Float16)a[j];
    hh[j] = hi;
    ll[j] = (_Float16)((a[j] - (float)hi) * 2048.0f);
  }
  *(half8*)(xh + base) = hh;
  *(half8*)(xl + base) = ll;
}

// ---------------- pre-split + transpose w -> [n 512][k 4608] fp16 hi/lo ----------------
__global__ __launch_bounds__(256) void k_split_w(const float* __restrict__ w,
                                                 _Float16* __restrict__ whT,
                                                 _Float16* __restrict__ wlT) {
  __shared__ _Float16 th[64][72];
  __shared__ _Float16 tl[64][72];
  const int kb = blockIdx.x;    // 0..71 (k tile of 64)
  const int cb = blockIdx.y;    // 0..7  (n tile of 64)
  const int t  = threadIdx.x;
  {
    const int r = t >> 2, cq = t & 3;
    float a[16];
    const float* wp = w + ((size_t)(kb * 64 + r) << 9) + cb * 64 + cq * 16;
#pragma unroll
    for (int j = 0; j < 4; ++j) *(float4*)&a[j << 2] = *(const float4*)(wp + (j << 2));
    half8 h0, h1, l0, l1;
#pragma unroll
    for (int j = 0; j < 8; ++j) {
      _Float16 hi = (_Float16)a[j];
      h0[j] = hi; l0[j] = (_Float16)((a[j] - (float)hi) * 2048.0f);
    }
#pragma unroll
    for (int j = 0; j < 8; ++j) {
      _Float16 hi = (_Float16)a[8 + j];
      h1[j] = hi; l1[j] = (_Float16)((a[8 + j] - (float)hi) * 2048.0f);
    }
    *(half8*)&th[r][cq * 16]     = h0;
    *(half8*)&th[r][cq * 16 + 8] = h1;
    *(half8*)&tl[r][cq * 16]     = l0;
    *(half8*)&tl[r][cq * 16 + 8] = l1;
  }
  __syncthreads();
  {
    const int c = t >> 2, kq = t & 3;
    half8 o0, o1, p0, p1;
#pragma unroll
    for (int j = 0; j < 8; ++j) { o0[j] = th[kq * 16 + j][c];     p0[j] = tl[kq * 16 + j][c]; }
#pragma unroll
    for (int j = 0; j < 8; ++j) { o1[j] = th[kq * 16 + 8 + j][c]; p1[j] = tl[kq * 16 + 8 + j][c]; }
    const size_t dst = (size_t)(cb * 64 + c) * 4608 + kb * 64 + kq * 16;
    *(half8*)(whT + dst)     = o0;
    *(half8*)(whT + dst + 8) = o1;
    *(half8*)(wlT + dst)     = p0;
    *(half8*)(wlT + dst + 8) = p1;
  }
}

// ---------------- conv (fast path): pre-split fp16 inputs, MFMA ----------------
#define APAD 40
__global__ __launch_bounds__(256, 2) void k_conv_pre(const _Float16* __restrict__ xh,
                                                     const _Float16* __restrict__ xl,
                                                     const _Float16* __restrict__ whT,
                                                     const _Float16* __restrict__ wlT,
                                                     const float* __restrict__ bias,
                                                     float* __restrict__ h) {
  __shared__ _Float16 Ah[128][APAD];
  __shared__ _Float16 Al[128][APAD];
  __shared__ _Float16 Bh[128][APAD];
  __shared__ _Float16 Bl[128][APAD];

  const int y  = blockIdx.x;
  const int nb = blockIdx.y;
  const int t  = threadIdx.x;
  const int wv = t >> 6, lane = t & 63;
  const int m0 = (wv >> 1) << 6;
  const int n0 = (wv & 1) << 6;
  const int fm = lane & 15;
  const int fq = lane >> 4;

  const int s_m = t >> 1;                 // pixel / n index 0..127
  const int s_h = (t & 1) << 4;           // channel-half 0/16

  f32x4 acc_hh[4][4];
  f32x4 acc_x[4][4];
#pragma unroll
  for (int i = 0; i < 4; ++i)
#pragma unroll
    for (int j = 0; j < 4; ++j) { acc_hh[i][j] = (f32x4)0.f; acc_x[i][j] = (f32x4)0.f; }

#pragma unroll 1
  for (int kb = 0; kb < 144; ++kb) {
    const int tap  = kb >> 4;
    const int ky   = tap / 3, kx = tap - ky * 3;
    const int cin0 = (kb & 15) << 5;

    // A stage: direct fp16 loads
    {
      const int yy = y + ky - 1;
      const int xx = s_m + kx - 1;
      if (yy >= 0 && yy < 128 && xx >= 0 && xx < 128) {
        const size_t off = (((size_t)((yy << 7) + xx)) << 9) + cin0 + s_h;
        *(half8*)&Ah[s_m][s_h]     = *(const half8*)(xh + off);
        *(half8*)&Ah[s_m][s_h + 8] = *(const half8*)(xh + off + 8);
        *(half8*)&Al[s_m][s_h]     = *(const half8*)(xl + off);
        *(half8*)&Al[s_m][s_h + 8] = *(const half8*)(xl + off + 8);
      } else {
        *(half8*)&Ah[s_m][s_h]     = (half8)(_Float16)0;
        *(half8*)&Ah[s_m][s_h + 8] = (half8)(_Float16)0;
        *(half8*)&Al[s_m][s_h]     = (half8)(_Float16)0;
        *(half8*)&Al[s_m][s_h + 8] = (half8)(_Float16)0;
      }
    }
    // B stage: direct fp16 loads from transposed weights
    {
      const size_t off = (size_t)(nb * 128 + s_m) * 4608 + tap * 512 + cin0 + s_h;
      *(half8*)&Bh[s_m][s_h]     = *(const half8*)(whT + off);
      *(half8*)&Bh[s_m][s_h + 8] = *(const half8*)(whT + off + 8);
      *(half8*)&Bl[s_m][s_h]     = *(const half8*)(wlT + off);
      *(half8*)&Bl[s_m][s_h + 8] = *(const half8*)(wlT + off + 8);
    }
    __syncthreads();

    half8 ah[4], al[4], bh[4], bl[4];
#pragma unroll
    for (int i = 0; i < 4; ++i) {
      ah[i] = *(const half8*)&Ah[m0 + (i << 4) + fm][fq << 3];
      al[i] = *(const half8*)&Al[m0 + (i << 4) + fm][fq << 3];
      bh[i] = *(const half8*)&Bh[n0 + (i << 4) + fm][fq << 3];
      bl[i] = *(const half8*)&Bl[n0 + (i << 4) + fm][fq << 3];
    }
#pragma unroll
    for (int mi = 0; mi < 4; ++mi)
#pragma unroll
      for (int ni = 0; ni < 4; ++ni) {
        acc_hh[mi][ni] = __builtin_amdgcn_mfma_f32_16x16x32_f16(ah[mi], bh[ni], acc_hh[mi][ni], 0, 0, 0);
        acc_x[mi][ni]  = __builtin_amdgcn_mfma_f32_16x16x32_f16(ah[mi], bl[ni], acc_x[mi][ni], 0, 0, 0);
        acc_x[mi][ni]  = __builtin_amdgcn_mfma_f32_16x16x32_f16(al[mi], bh[ni], acc_x[mi][ni], 0, 0, 0);
      }
    __syncthreads();
  }

  const float inv2048 = 1.0f / 2048.0f;
#pragma unroll
  for (int mi = 0; mi < 4; ++mi)
#pragma unroll
    for (int ni = 0; ni < 4; ++ni) {
      const int col = n0 + (ni << 4) + fm;
      const float bb = bias[(nb << 7) + col];
#pragma unroll
      for (int r = 0; r < 4; ++r) {
        const int row = m0 + (mi << 4) + (fq << 2) + r;
        float v = acc_hh[mi][ni][r] + acc_x[mi][ni][r] * inv2048 + bb;
        h[(((size_t)((y << 7) + row)) << 9) + (nb << 7) + col] = fmaxf(v, 0.f);
      }
    }
}

// ---------------- conv (fallback): in-kernel split (round-2 version) ----------------
__global__ __launch_bounds__(256, 2) void k_conv_fb(const float* __restrict__ x,
                                                    const float* __restrict__ w,
                                                    const float* __restrict__ bias,
                                                    float* __restrict__ h) {
  __shared__ _Float16 Ah[128][APAD];
  __shared__ _Float16 Al[128][APAD];
  __shared__ _Float16 Bh[128][APAD];
  __shared__ _Float16 Bl[128][APAD];

  const int y  = blockIdx.x;
  const int nb = blockIdx.y;
  const int t  = threadIdx.x;
  const int wv = t >> 6, lane = t & 63;
  const int m0 = (wv >> 1) << 6;
  const int n0 = (wv & 1) << 6;
  const int fm = lane & 15;
  const int fq = lane >> 4;
  const int sa_m = t >> 1;
  const int sa_h = (t & 1) << 4;
  const int sb_n = t & 127;
  const int sb_kg = (t >> 7) << 4;

  f32x4 acc_hh[4][4];
  f32x4 acc_x[4][4];
#pragma unroll
  for (int i = 0; i < 4; ++i)
#pragma unroll
    for (int j = 0; j < 4; ++j) { acc_hh[i][j] = (f32x4)0.f; acc_x[i][j] = (f32x4)0.f; }

#pragma unroll 1
  for (int kb = 0; kb < 144; ++kb) {
    const int tap  = kb >> 4;
    const int ky   = tap / 3, kx = tap - ky * 3;
    const int cin0 = (kb & 15) << 5;
    {
      const int yy = y + ky - 1;
      const int xx = sa_m + kx - 1;
      float av[16];
      if (yy >= 0 && yy < 128 && xx >= 0 && xx < 128) {
        const float* ap = x + (((size_t)((yy << 7) + xx)) << 9) + cin0 + sa_h;
#pragma unroll
        for (int j = 0; j < 4; ++j) *(float4*)&av[j << 2] = *(const float4*)(ap + (j << 2));
      } else {
#pragma unroll
        for (int j = 0; j < 16; ++j) av[j] = 0.f;
      }
      half8 h0, h1, l0, l1;
#pragma unroll
      for (int j = 0; j < 8; ++j) {
        _Float16 hi = (_Float16)av[j];
        h0[j] = hi; l0[j] = (_Float16)((av[j] - (float)hi) * 2048.0f);
      }
#pragma unroll
      for (int j = 0; j < 8; ++j) {
        _Float16 hi = (_Float16)av[8 + j];
        h1[j] = hi; l1[j] = (_Float16)((av[8 + j] - (float)hi) * 2048.0f);
      }
      *(half8*)&Ah[sa_m][sa_h]     = h0;
      *(half8*)&Ah[sa_m][sa_h + 8] = h1;
      *(half8*)&Al[sa_m][sa_h]     = l0;
      *(half8*)&Al[sa_m][sa_h + 8] = l1;
    }
    {
      const float* bp = w + ((size_t)(tap * 512 + cin0 + sb_kg) << 9) + (nb << 7) + sb_n;
      float bv[16];
#pragma unroll
      for (int j = 0; j < 16; ++j) bv[j] = bp[(size_t)j << 9];
      half8 h0, h1, l0, l1;
#pragma unroll
      for (int j = 0; j < 8; ++j) {
        _Float16 hi = (_Float16)bv[j];
        h0[j] = hi; l0[j] = (_Float16)((bv[j] - (float)hi) * 2048.0f);
      }
#pragma unroll
      for (int j = 0; j < 8; ++j) {
        _Float16 hi = (_Float16)bv[8 + j];
        h1[j] = hi; l1[j] = (_Float16)((bv[8 + j] - (float)hi) * 2048.0f);
      }
      *(half8*)&Bh[sb_n][sb_kg]     = h0;
      *(half8*)&Bh[sb_n][sb_kg + 8] = h1;
      *(half8*)&Bl[sb_n][sb_kg]     = l0;
      *(half8*)&Bl[sb_n][sb_kg + 8] = l1;
    }
    __syncthreads();
    half8 ah[4], al[4], bh[4], bl[4];
#pragma unroll
    for (int i = 0; i < 4; ++i) {
      ah[i] = *(const half8*)&Ah[m0 + (i << 4) + fm][fq << 3];
      al[i] = *(const half8*)&Al[m0 + (i << 4) + fm][fq << 3];
      bh[i] = *(const half8*)&Bh[n0 + (i << 4) + fm][fq << 3];
      bl[i] = *(const half8*)&Bl[n0 + (i << 4) + fm][fq << 3];
    }
#pragma unroll
    for (int mi = 0; mi < 4; ++mi)
#pragma unroll
      for (int ni = 0; ni < 4; ++ni) {
        acc_hh[mi][ni] = __builtin_amdgcn_mfma_f32_16x16x32_f16(ah[mi], bh[ni], acc_hh[mi][ni], 0, 0, 0);
        acc_x[mi][ni]  = __builtin_amdgcn_mfma_f32_16x16x32_f16(ah[mi], bl[ni], acc_x[mi][ni], 0, 0, 0);
        acc_x[mi][ni]  = __builtin_amdgcn_mfma_f32_16x16x32_f16(al[mi], bh[ni], acc_x[mi][ni], 0, 0, 0);
      }
    __syncthreads();
  }
  const float inv2048 = 1.0f / 2048.0f;
#pragma unroll
  for (int mi = 0; mi < 4; ++mi)
#pragma unroll
    for (int ni = 0; ni < 4; ++ni) {
      const int col = n0 + (ni << 4) + fm;
      const float bb = bias[(nb << 7) + col];
#pragma unroll
      for (int r = 0; r < 4; ++r) {
        const int row = m0 + (mi << 4) + (fq << 2) + r;
        float v = acc_hh[mi][ni][r] + acc_x[mi][ni][r] * inv2048 + bb;
        h[(((size_t)((y << 7) + row)) << 9) + (nb << 7) + col] = fmaxf(v, 0.f);
      }
    }
}

// ---------------- heads (+ hist1 fold) ----------------
__global__ __launch_bounds__(256) void k_heads(const float* __restrict__ h,
        const float4* __restrict__ w54, const float* __restrict__ b54,
        float* __restrict__ out0, float* __restrict__ out1, float* __restrict__ out3,
        float4* __restrict__ boxes, u32* __restrict__ keys, u32* __restrict__ hist1,
        const int* __restrict__ p_ih, const int* __restrict__ p_iw,
        const int* __restrict__ p_sc, AB ab) {
  __shared__ float hl[16 * 512];
  __shared__ float vals[16][64];
  const int t = threadIdx.x;
  const int wv = t >> 6, lane = t & 63;
  const int pbase = blockIdx.x << 4;

#pragma unroll
  for (int j = 0; j < 8; ++j) {
    const int f = (j << 8) + t;
    ((float4*)hl)[f] = ((const float4*)(h + ((size_t)pbase << 9)))[f];
  }
  __syncthreads();

  const float* hp = hl + ((wv << 2) << 9);
  float a0 = 0.f, a1 = 0.f, a2 = 0.f, a3 = 0.f;
#pragma unroll 4
  for (int kq = 0; kq < 128; ++kq) {
    const float4 wvv = w54[(kq << 6) + lane];
    const float4 h0 = *(const float4*)(hp + (kq << 2));
    const float4 h1 = *(const float4*)(hp + 512 + (kq << 2));
    const float4 h2 = *(const float4*)(hp + 1024 + (kq << 2));
    const float4 h3 = *(const float4*)(hp + 1536 + (kq << 2));
    a0 += h0.x * wvv.x + h0.y * wvv.y + h0.z * wvv.z + h0.w * wvv.w;
    a1 += h1.x * wvv.x + h1.y * wvv.y + h1.z * wvv.z + h1.w * wvv.w;
    a2 += h2.x * wvv.x + h2.y * wvv.y + h2.z * wvv.z + h2.w * wvv.w;
    a3 += h3.x * wvv.x + h3.y * wvv.y + h3.z * wvv.z + h3.w * wvv.w;
  }
  const float bb = b54[lane];
  float av[4] = {a0 + bb, a1 + bb, a2 + bb, a3 + bb};
#pragma unroll
  for (int px = 0; px < 4; ++px) {
    const int p = pbase + (wv << 2) + px;
    vals[(wv << 2) + px][lane] = av[px];
    if (lane < 36) out0[p * 36 + lane] = av[px];
    else if (lane < 54) out1[p * 18 + lane - 36] = av[px];
  }
  __syncthreads();

  if (lane < 36) {
    const int px = lane / 9, a = lane - px * 9;
    const int p = pbase + (wv << 2) + px;
    const float* vv = vals[(wv << 2) + px];
    const float l0 = vv[(a << 2) + 0], l1 = vv[(a << 2) + 1];
    const float l2 = vv[(a << 2) + 2], l3 = vv[(a << 2) + 3];
    const float s0 = vv[36 + (a << 1)], s1 = vv[37 + (a << 1)];
    const int yq = p >> 7, xq = p & 127;
    const float fy = (float)(yq << 4), fx = (float)(xq << 4);
    const float ay1 = ab.v[(a << 2) + 0] + fy;
    const float ax1 = ab.v[(a << 2) + 1] + fx;
    const float ay2 = ab.v[(a << 2) + 2] + fy;
    const float ax2 = ab.v[(a << 2) + 3] + fx;
    const int idx = p * 9 + a;
    *(float4*)(out3 + ((size_t)idx << 2)) = make_float4(ay1, ax1, ay2, ax2);

    const float sh = ay2 - ay1, sw = ax2 - ax1;
    const float scy = ay1 + 0.5f * sh, scx = ax1 + 0.5f * sw;
    const float cy = l0 * sh + scy, cx = l1 * sw + scx;
    const float bh = expf(l2) * sh, bw = expf(l3) * sw;
    const float IH = (float)p_ih[0], IW = (float)p_iw[0];
    float d0 = fminf(fmaxf(cy - 0.5f * bh, 0.f), IH);
    float d1 = fminf(fmaxf(cx - 0.5f * bw, 0.f), IW);
    float d2 = fminf(fmaxf(cy + 0.5f * bh, 0.f), IH);
    float d3 = fminf(fmaxf(cx + 0.5f * bw, 0.f), IW);
    boxes[idx] = make_float4(d0, d1, d2, d3);

    const float minsz = 16.f * (float)p_sc[0];
    const bool keep = (d2 - d0 >= minsz) && (d3 - d1 >= minsz);
    const float mx = fmaxf(s0, s1);
    const float e0 = expf(s0 - mx), e1 = expf(s1 - mx);
    const float fg = e1 / (e0 + e1);
    const float sc = keep ? fg : -INFINITY;
    const u32 u = __float_as_uint(sc);
    const u32 key = (u & 0x80000000u) ? ~u : (u | 0x80000000u);
    keys[idx] = key;
    atomicAdd(&hist1[key >> 16], 1u);
  }
}

// ---------------- top-6000: two-level radix select ----------------
__global__ void k_hist2(const u32* __restrict__ keys, const u32* __restrict__ ctrl,
                        u32* __restrict__ hist2) {
  const u32 b1 = ctrl[0];
  int i = blockIdx.x * blockDim.x + threadIdx.x;
  if (i < N_ANC) {
    const u32 k = keys[i];
    if ((k >> 16) == b1) atomicAdd(&hist2[k & 0xFFFFu], 1u);
  }
}

__global__ __launch_bounds__(1024) void k_findcut(const u32* __restrict__ hist,
                                                  u32* __restrict__ ctrl, int mode) {
  __shared__ u32 csum[1024];
  __shared__ u32 suf[1024];
  const int t = threadIdx.x;
  const u32 target = (mode == 0) ? (u32)N_PRE : ((u32)N_PRE - ctrl[1]);
  const int base = t << 6;
  u32 s = 0;
  for (int i = 0; i < 64; ++i) s += hist[base + i];
  csum[t] = s;
  suf[t] = s;
  __syncthreads();
  for (int off = 1; off < 1024; off <<= 1) {
    u32 add = (t + off < 1024) ? suf[t + off] : 0u;
    __syncthreads();
    suf[t] += add;
    __syncthreads();
  }
  const u32 excl = suf[t] - csum[t];
  if (excl < target && target <= suf[t]) {
    u32 cum = excl;
    int bkt = base;
    for (int i = 63; i >= 0; --i) {
      const u32 hh = hist[base + i];
      if (cum < target && target <= cum + hh) { bkt = base + i; break; }
      cum += hh;
    }
    if (mode == 0) { ctrl[0] = (u32)bkt; ctrl[1] = cum; }
    else {
      const u32 Kstar = (ctrl[0] << 16) | (u32)bkt;
      const u32 A = ctrl[1] + cum;
      u32 need = (u32)N_PRE - A;
      if (Kstar == KEY_NEGINF) need = 0u;
      ctrl[2] = Kstar; ctrl[3] = A; ctrl[4] = need;
      ctrl[7] = A + need;   // L
    }
  }
}

__global__ void k_compact(const u32* __restrict__ keys, u32* __restrict__ ctrl,
                          u64* __restrict__ cand) {
  const u32 Kstar = ctrl[2];
  const u32 need  = ctrl[4];
  int i = blockIdx.x * blockDim.x + threadIdx.x;
  if (i >= N_ANC) return;
  const u32 k = keys[i];
  if (k > Kstar) {
    const u32 pos = atomicAdd(&ctrl[5], 1u);
    cand[pos] = ((u64)k << 32) | (u64)(u32)(~(u32)i);
  } else if (k == Kstar && need != 0u) {
    const u32 pos = atomicAdd(&ctrl[6], 1u);
    if (pos < (u32)TIE_CAP) cand[TIE_BASE + pos] = ((u64)Kstar << 32) | (u64)(u32)(~(u32)i);
  }
}

// rank-placement sort: sbox[rank(v_i)] = boxes[idx(v_i)] for rank < L.
__global__ __launch_bounds__(128) void k_rank(const u32* __restrict__ ctrl,
                                              const u64* __restrict__ cand,
                                              const float4* __restrict__ boxes,
                                              float4* __restrict__ sbox) {
  __shared__ u32 wred[2];
  const u32 A   = ctrl[3];
  const u32 tcc = min(ctrl[6], (u32)TIE_CAP);
  const u32 C   = A + tcc;
  const u32 L   = ctrl[7];
  const u32 i   = blockIdx.x;
  if (i >= C) return;
  const u64 v = (i < A) ? cand[i] : cand[TIE_BASE + (i - A)];
  const int t = threadIdx.x;
  u32 cnt = 0;
  for (u32 j = t; j < A; j += 128) cnt += (cand[j] > v);
  for (u32 j = t; j < tcc; j += 128) cnt += (cand[TIE_BASE + j] > v);
#pragma unroll
  for (int off = 32; off > 0; off >>= 1) cnt += __shfl_xor(cnt, off);
  if ((t & 63) == 0) wred[t >> 6] = cnt;
  __syncthreads();
  if (t == 0) {
    const u32 rank = wred[0] + wred[1];
    if (rank < L) {
      const u32 idx = ~((u32)(v & 0xFFFFFFFFULL));
      sbox[rank] = boxes[idx];
    }
  }
}

// ---------------- NMS ----------------
__global__ __launch_bounds__(64) void k_mask(const u32* __restrict__ ctrl,
                                             const float4* __restrict__ sbox,
                                             u64* __restrict__ mask) {
  const int L = (int)ctrl[7];
  const int cw = blockIdx.x;       // col word 0..93
  const int rb = blockIdx.y;       // row block 0..93
  if (cw < rb) return;             // lower-triangle words never pass above-mask filter
  if (rb * 64 >= L) return;
  const int lane = threadIdx.x;
  const int j = cw * 64 + lane;
  const bool jok = (j < L);
  const float4 cb = jok ? sbox[j] : make_float4(0.f, 0.f, 0.f, 0.f);
  const float careaJ = (cb.z - cb.x) * (cb.w - cb.y);
  const int rbase = rb * 64;
  const float4 rbx = (rbase + lane < L) ? sbox[rbase + lane] : make_float4(0.f, 0.f, 0.f, 0.f);
  const int rmax = min(64, L - rbase);
  for (int r = 0; r < rmax; ++r) {
    const float ry1 = __shfl(rbx.x, r), rx1 = __shfl(rbx.y, r);
    const float ry2 = __shfl(rbx.z, r), rx2 = __shfl(rbx.w, r);
    const float ra = (ry2 - ry1) * (rx2 - rx1);
    const float iy1 = fmaxf(cb.x, ry1), ix1 = fmaxf(cb.y, rx1);
    const float iy2 = fminf(cb.z, ry2), ix2 = fminf(cb.w, rx2);
    const float inter = fmaxf(iy2 - iy1, 0.f) * fmaxf(ix2 - ix1, 0.f);
    const float iou = inter / (careaJ + ra - inter + 1e-9f);
    const bool bit = jok && (iou > 0.7f);
    const u64 bal = __ballot(bit);
    if (lane == 0) mask[(size_t)(rbase + r) * 94 + cw] = bal;
  }
}

__device__ inline u64 valid_mask_fn(int base, int L) {
  const int r = L - base;
  if (r <= 0) return 0ULL;
  if (r >= 64) return ~0ULL;
  return (1ULL << r) - 1ULL;
}
__device__ inline u64 above_mask_fn(int base, int i) {
  if (i < base) return ~0ULL;
  const int s = i - base + 1;
  if (s >= 64) return 0ULL;
  return (~0ULL) << s;
}

__global__ __launch_bounds__(64) void k_greedy(const u32* __restrict__ ctrl,
                                               const float* __restrict__ sboxf,
                                               const u64* __restrict__ mask,
                                               float* __restrict__ roi) {
  const int lane = threadIdx.x;
  const int L = (int)ctrl[7];
  const int base0 = lane << 6;
  const int base1 = (64 + lane) << 6;
  const u64 v0 = valid_mask_fn(base0, L);
  const u64 v1 = (lane < 30) ? valid_mask_fn(base1, L) : 0ULL;
  u64 rem0 = 0ULL, rem1 = 0ULL;
  int i = (L > 0) ? 0 : -1;
  int kept = 0;
  while (i >= 0 && kept < 300) {
    if (lane < 4) roi[kept * 4 + lane] = sboxf[(size_t)i * 4 + lane];
    ++kept;
    rem0 |= mask[(size_t)i * 94 + lane];
    if (lane < 30) rem1 |= mask[(size_t)i * 94 + 64 + lane];
    const u64 f0 = ~rem0 & v0 & above_mask_fn(base0, i);
    const u64 f1 = ~rem1 & v1 & above_mask_fn(base1, i);
    int c0 = f0 ? (base0 + (int)__builtin_ctzll(f0)) : 0x7FFFFFFF;
    int c1 = f1 ? (base1 + (int)__builtin_ctzll(f1)) : 0x7FFFFFFF;
    int c = min(c0, c1);
#pragma unroll
    for (int off = 1; off < 64; off <<= 1) c = min(c, __shfl_xor(c, off));
    i = (c == 0x7FFFFFFF) ? -1 : c;
  }
}

// ---------------- launch ----------------
extern "C" void kernel_launch(void* const* d_in, const int* in_sizes, int n_in,
                              void* d_out, int out_size, void* d_ws, size_t ws_size,
                              hipStream_t stream) {
  (void)in_sizes; (void)n_in; (void)out_size;
  if (ws_size < BASE_NEEDED) return;
  const bool fast = (ws_size >= FULL_NEEDED);

  const float* x       = (const float*)d_in[0];
  const float* conv_w  = (const float*)d_in[1];
  const float* conv_b  = (const float*)d_in[2];
  const float* loc_w   = (const float*)d_in[3];
  const float* loc_b   = (const float*)d_in[4];
  const float* score_w = (const float*)d_in[5];
  const float* score_b = (const float*)d_in[6];
  const int* p_ih = (const int*)d_in[7];
  const int* p_iw = (const int*)d_in[8];
  const int* p_sc = (const int*)d_in[9];

  float* out0 = (float*)d_out;
  float* out1 = out0 + 589824;
  float* roi  = out1 + 294912;
  float* out3 = roi + 1200;

  char* ws = (char*)d_ws;
  float*     h     = (float*)(ws + OFF_H);
  float4*    boxes = (float4*)(ws + OFF_BOXES);
  u32*       keys  = (u32*)(ws + OFF_KEYS);
  float*     w54   = (float*)(ws + OFF_W54);
  float*     b54   = (float*)(ws + OFF_B54);
  u32*       hist1 = (u32*)(ws + OFF_HIST1);
  u32*       hist2 = (u32*)(ws + OFF_HIST2);
  u32*       ctrl  = (u32*)(ws + OFF_CTRL);
  u64*       cand  = (u64*)(ws + OFF_CAND);
  float4*    sbox  = (float4*)(ws + OFF_SBOX);
  u64*       mask  = (u64*)(ws + OFF_MASK);
  _Float16*  xh    = (_Float16*)(ws + OFF_XH);
  _Float16*  xl    = (_Float16*)(ws + OFF_XL);
  _Float16*  whT   = (_Float16*)(ws + OFF_WHT);
  _Float16*  wlT   = (_Float16*)(ws + OFF_WLT);

  AB ab;
  {
    const double ratios[3] = {0.5, 1.0, 2.0};
    const double scales[3] = {8.0, 16.0, 32.0};
    for (int i = 0; i < 3; ++i)
      for (int j = 0; j < 3; ++j) {
        const double hh = 16.0 * scales[j] * sqrt(ratios[i]);
        const double wwv = 16.0 * scales[j] * sqrt(1.0 / ratios[i]);
        const int a = i * 3 + j;
        ab.v[a * 4 + 0] = (float)(8.0 - hh / 2.0);
        ab.v[a * 4 + 1] = (float)(8.0 - wwv / 2.0);
        ab.v[a * 4 + 2] = (float)(8.0 + hh / 2.0);
        ab.v[a * 4 + 3] = (float)(8.0 + wwv / 2.0);
      }
  }

  hipLaunchKernelGGL(k_init, dim3(256), dim3(256), 0, stream,
                     hist1, hist2, ctrl, roi, w54, b54, loc_w, loc_b, score_w, score_b);
  if (fast) {
    hipLaunchKernelGGL(k_split_x, dim3(4096), dim3(256), 0, stream, x, xh, xl);
    hipLaunchKernelGGL(k_split_w, dim3(72, 8), dim3(256), 0, stream, conv_w, whT, wlT);
    hipLaunchKernelGGL(k_conv_pre, dim3(128, 4), dim3(256), 0, stream, xh, xl, whT, wlT, conv_b, h);
  } else {
    hipLaunchKernelGGL(k_conv_fb, dim3(128, 4), dim3(256), 0, stream, x, conv_w, conv_b, h);
  }
  hipLaunchKernelGGL(k_heads, dim3(1024), dim3(256), 0, stream,
                     h, (const float4*)w54, b54, out0, out1, out3, boxes, keys, hist1,
                     p_ih, p_iw, p_sc, ab);
  hipLaunchKernelGGL(k_findcut, dim3(1), dim3(1024), 0, stream, hist1, ctrl, 0);
  hipLaunchKernelGGL(k_hist2, dim3(576), dim3(256), 0, stream, keys, ctrl, hist2);
  hipLaunchKernelGGL(k_findcut, dim3(1), dim3(1024), 0, stream, hist2, ctrl, 1);
  hipLaunchKernelGGL(k_compact, dim3(576), dim3(256), 0, stream, keys, ctrl, cand);
  hipLaunchKernelGGL(k_rank, dim3(TIE_BASE + TIE_CAP), dim3(128), 0, stream, ctrl, cand, boxes, sbox);
  hipLaunchKernelGGL(k_mask, dim3(94, 94), dim3(64), 0, stream, ctrl, sbox, mask);
  hipLaunchKernelGGL(k_greedy, dim3(1), dim3(64), 0, stream, ctrl, (const float*)sbox, mask, roi);
}